// Round 13
// baseline (144.349 us; speedup 1.0000x reference)
//
#include <hip/hip_runtime.h>
#include <hip/hip_bf16.h>

#define N_  32
#define C_  64
#define T_  300
#define V_  25
#define TV  (T_*V_)        // 7500
#define CTV (C_*TV)        // 480000
#define NELEM (N_*CTV)     // 15360000
#define CNTF 240000.0f

typedef float f32x4 __attribute__((ext_vector_type(4)));
typedef short bf16x8 __attribute__((ext_vector_type(8)));
typedef short s4v __attribute__((ext_vector_type(4)));
typedef short s8v __attribute__((ext_vector_type(8)));

__device__ __forceinline__ unsigned short f2bf(float f) {
    unsigned u = __float_as_uint(f);
    unsigned r = u + 0x7fffu + ((u >> 16) & 1u);
    return (unsigned short)(r >> 16);
}
__device__ __forceinline__ float bf2f(unsigned short u) {
    return __uint_as_float(((unsigned)u) << 16);
}
// HW packed f32->bf16 (RNE)
__device__ __forceinline__ unsigned cvt_pk(float lo, float hi) {
    unsigned r;
    asm("v_cvt_pk_bf16_f32 %0, %1, %2" : "=v"(r) : "v"(lo), "v"(hi));
    return r;
}

// ---------------------------------------------------------------------------
// k_prep: weights -> bf16 MFMA layouts; A -> transposed bf16 [k3][w32][v40].
// ---------------------------------------------------------------------------
__global__ __launch_bounds__(256) void k_prep(
    const float* __restrict__ conv_w, const float* __restrict__ tw,
    const float* __restrict__ A,
    unsigned short* __restrict__ w2b, unsigned short* __restrict__ twb,
    unsigned short* __restrict__ ashA)
{
    int tid = blockIdx.x*256 + threadIdx.x;
    for (int e = tid; e < 20480; e += 8192) {
        int ks = e >> 11, c = (e >> 5) & 63, kk = e & 31;
        w2b[e] = f2bf(conv_w[(((ks>>1)*64 + c)*64) + (ks&1)*32 + kk]);
    }
    for (int e = tid; e < 36864; e += 8192) {
        int gi = e >> 11, c = (e >> 5) & 63, kk = e & 31;
        int dt = gi >> 1, ks = gi & 1;
        twb[e] = f2bf(tw[(c*64 + 32*ks + kk)*9 + dt]);
    }
    for (int e = tid; e < 3840; e += 8192) {
        int k = e / 1280, r = e - k*1280, w = r / 40, v = r % 40;
        float val = (w < 25 && v < 25) ? A[k*625 + v*25 + w] : 0.f;
        ashA[e] = f2bf(val);
    }
}

// ---------------------------------------------------------------------------
// k_prepn: per-n staging precompute. grid 32 (one block per n).
// bshB[n][k2][w32][v40] = lam*B[n][k][v][w] bf16 (pads zero);
// csumN[n][k5][w32] = colsum of aeff (0 for w>=25).
// ---------------------------------------------------------------------------
__global__ __launch_bounds__(256) void k_prepn(
    const float* __restrict__ A, const float* __restrict__ B,
    const float* __restrict__ lamda,
    unsigned short* __restrict__ bshB, float* __restrict__ csumN)
{
    const int n = blockIdx.x, tid = threadIdx.x;
    const float lam = lamda[0];
    unsigned short* dst = bshB + n*2560;
    {
        s8v z8 = {0,0,0,0,0,0,0,0};
        for (int e = tid; e < 320; e += 256) *(s8v*)&dst[e*8] = z8;
    }
    __syncthreads();
    for (int e = tid; e < 1250; e += 256) {
        int k = e / 625, r = e - k*625, v = r / 25, w = r - v*25;
        dst[k*1280 + w*40 + v] = f2bf(lam * B[((n<<1) + k)*625 + r]);
    }
    for (int e = tid; e < 160; e += 256) {
        int k = e / 32, w = e % 32;
        float s = 0.f;
        if (w < 25) {
            if (k < 3) { for (int v = 0; v < 25; ++v) s += bf2f(f2bf(A[k*625 + v*25 + w])); }
            else       { for (int v = 0; v < 25; ++v) s += bf2f(f2bf(lam * B[((n<<1)+(k-3))*625 + v*25 + w])); }
        }
        csumN[n*160 + e] = s;
    }
}

// ---------------------------------------------------------------------------
// k_gcn v7: r12 loop structure, TC=5, but NO ash LDS — step1 aeff B-frags
// read directly from global ashA/bshB (L2-hot, loop-invariant -> compiler can
// hoist to regs). LDS = zsh only (20.5 KB) -> up to 7 blocks/CU.
// ---------------------------------------------------------------------------
__global__ __launch_bounds__(256) void k_gcn(
    const float* __restrict__ x,
    const unsigned short* __restrict__ ashA, const unsigned short* __restrict__ bshB,
    const float* __restrict__ csumN,
    const unsigned short* __restrict__ w2b, const float* __restrict__ conv_b,
    unsigned short* __restrict__ gout, float* __restrict__ stats3)
{
    __shared__ unsigned short zsh[10496];  // [w32][j328]

    const int tb = blockIdx.x, n = blockIdx.y;
    const int t0 = tb*5;
    const int tid = threadIdx.x;
    const int lane = tid & 63, wv = tid >> 6;
    const int lg = lane >> 4, lr = lane & 15;
    const int crow = lr + 16*wv;
    const int cbase = 16*wv + 4*lg;

    bf16x8 wfrag[10];
    #pragma unroll
    for (int ks = 0; ks < 10; ++ks)
        wfrag[ks] = *(const bf16x8*)&w2b[(ks*64 + crow)*32 + 8*lg];

    // bias-through-adjacency terms from precomputed csum (L2-hot globals)
    const float* csum = csumN + n*160;
    float bs0[4], bs1[4];
    #pragma unroll
    for (int r = 0; r < 4; ++r) {
        float s0 = 0.f, s1 = 0.f;
        #pragma unroll
        for (int k = 0; k < 5; ++k) {
            float cb = conv_b[k*64 + cbase + r];
            s0 += cb * csum[k*32 + lr];
            s1 += cb * csum[k*32 + lr + 16];
        }
        bs0[r] = s0; bs1[r] = s1;
    }

    float sacc[4] = {0,0,0,0}, qacc[4] = {0,0,0,0};

    const float* xrow = x + n*CTV + crow*TV + t0*V_;
    float xf[8];
    #pragma unroll
    for (int i = 0; i < 8; ++i) { int v = 8*lg + i; xf[i] = (v < 25) ? xrow[v] : 0.f; }

    for (int tl = 0; tl < 5; ++tl) {
        union { bf16x8 v; unsigned u[4]; } xu;
        #pragma unroll
        for (int p = 0; p < 4; ++p) xu.u[p] = cvt_pk(xf[2*p], xf[2*p+1]);
        bf16x8 xfrag = xu.v;
        if (tl < 4) {
            const float* xn = xrow + (tl+1)*V_;
            #pragma unroll
            for (int i = 0; i < 8; ++i) { int v = 8*lg + i; xf[i] = (v < 25) ? xn[v] : 0.f; }
        }
        // step 1: z tiles -> zsh (aeff frags from global, loop-invariant)
        #pragma unroll
        for (int k = 0; k < 5; ++k)
        #pragma unroll
        for (int nt = 0; nt < 2; ++nt) {
            const unsigned short* asrc = (k < 3) ? (ashA + k*1280)
                                                 : (bshB + n*2560 + (k-3)*1280);
            bf16x8 bfrag = *(const bf16x8*)&asrc[(lr + 16*nt)*40 + 8*lg];
            f32x4 z = {0.f,0.f,0.f,0.f};
            z = __builtin_amdgcn_mfma_f32_16x16x32_bf16(xfrag, bfrag, z, 0, 0, 0);
            uint2 zz;
            zz.x = cvt_pk(z[0], z[1]);
            zz.y = cvt_pk(z[2], z[3]);
            *(uint2*)&zsh[(lr + 16*nt)*328 + k*64 + 16*wv + 4*lg] = zz;
        }
        __syncthreads();
        // step 2: g = W2 @ z
        f32x4 acc0 = {0.f,0.f,0.f,0.f}, acc1 = {0.f,0.f,0.f,0.f};
        #pragma unroll
        for (int ks = 0; ks < 10; ++ks) {
            bf16x8 b0 = *(const bf16x8*)&zsh[lr*328 + 32*ks + 8*lg];
            bf16x8 b1 = *(const bf16x8*)&zsh[(lr+16)*328 + 32*ks + 8*lg];
            acc0 = __builtin_amdgcn_mfma_f32_16x16x32_bf16(wfrag[ks], b0, acc0, 0, 0, 0);
            acc1 = __builtin_amdgcn_mfma_f32_16x16x32_bf16(wfrag[ks], b1, acc1, 0, 0, 0);
        }
        // epilogue: bias, stats, direct global stores
        float v0a[4], v1a[4];
        #pragma unroll
        for (int r = 0; r < 4; ++r) {
            v0a[r] = acc0[r] + bs0[r];
            v1a[r] = acc1[r] + bs1[r];
            sacc[r] += v0a[r] + (lr < 9 ? v1a[r] : 0.f);
            qacc[r] += v0a[r]*v0a[r] + (lr < 9 ? v1a[r]*v1a[r] : 0.f);
        }
        unsigned short* grow = gout + (size_t)(n*300 + t0 + tl)*1600;
        uint2 g0, g1;
        g0.x = cvt_pk(v0a[0], v0a[1]); g0.y = cvt_pk(v0a[2], v0a[3]);
        g1.x = cvt_pk(v1a[0], v1a[1]); g1.y = cvt_pk(v1a[2], v1a[3]);
        *(uint2*)&grow[lr*64 + cbase] = g0;
        if (lr < 9) *(uint2*)&grow[(lr+16)*64 + cbase] = g1;
        __syncthreads();
    }

    #pragma unroll
    for (int r = 0; r < 4; ++r) {
        float s = sacc[r], q = qacc[r];
        s += __shfl_xor(s, 1); s += __shfl_xor(s, 2);
        s += __shfl_xor(s, 4); s += __shfl_xor(s, 8);
        q += __shfl_xor(q, 1); q += __shfl_xor(q, 2);
        q += __shfl_xor(q, 4); q += __shfl_xor(q, 8);
        if (lr == 0) {
            stats3[(n*60 + tb)*128 + cbase + r] = s;
            stats3[(n*60 + tb)*128 + 64 + cbase + r] = q;
        }
    }
}

// ---------------------------------------------------------------------------
// k_fin: reduce per-block stats -> BN scale/shift. grid 64.
// ---------------------------------------------------------------------------
__global__ __launch_bounds__(256) void k_fin(
    const float* __restrict__ src, int count, float* __restrict__ sbo,
    const float* __restrict__ gma, const float* __restrict__ bta)
{
    const int c = blockIdx.x, tid = threadIdx.x;
    float s = 0.f, q = 0.f;
    for (int b = tid; b < count; b += 256) {
        s += src[b*128 + c];
        q += src[b*128 + 64 + c];
    }
    #pragma unroll
    for (int m = 1; m < 64; m <<= 1) { s += __shfl_xor(s, m); q += __shfl_xor(q, m); }
    __shared__ float rs[4], rq[4];
    if ((tid & 63) == 0) { rs[tid>>6] = s; rq[tid>>6] = q; }
    __syncthreads();
    if (tid == 0) {
        s = rs[0]+rs[1]+rs[2]+rs[3]; q = rq[0]+rq[1]+rq[2]+rq[3];
        float mean = s / CNTF, var = q / CNTF - mean*mean;
        float sc = gma[c] * rsqrtf(var + 1e-5f);
        sbo[c] = sc;
        sbo[64 + c] = bta[c] - mean*sc;
    }
}

// ---------------------------------------------------------------------------
// k_tcn v6: grid (59,32), 256 thr = 4 waves. v5 structure, but bn1+relu
// folded into the staging loop (reads g directly; k_bn1/p eliminated).
// ---------------------------------------------------------------------------
__global__ __launch_bounds__(256) void k_tcn(
    const unsigned short* __restrict__ g, const float* __restrict__ sb,
    const unsigned short* __restrict__ twb, const float* __restrict__ tb,
    unsigned short* __restrict__ hout, float* __restrict__ stats4)
{
    __shared__ unsigned short lds[328*64];   // 41984 B; reused as hbuf[64][136]
    __shared__ float sbs[128];

    const int bj = blockIdx.x, n = blockIdx.y;
    const int j0 = bj*128;
    const int tid = threadIdx.x;
    const int lane = tid & 63, ct = tid >> 6;
    const int lg = lane >> 4, lr = lane & 15;
    const int cA = ct*16 + lr;
    const int cbase = ct*16 + 4*lg;

    if (tid < 128) sbs[tid] = sb[tid];
    __syncthreads();

    // stage rows j = j0-100 .. j0+227 of p = relu(bn1(g)), zero outside
    for (int e = tid; e < 2624; e += 256) {
        int row = e >> 3, q = e & 7;
        int gr = j0 - 100 + row;
        uint4 pk4 = {0,0,0,0};
        if (gr >= 0 && gr < 7500) {
            s8v raw = *(const s8v*)&g[((size_t)n*7500 + gr)*64 + q*8];
            float f[8];
            #pragma unroll
            for (int j = 0; j < 8; ++j)
                f[j] = fmaxf(fmaf(bf2f((unsigned short)raw[j]), sbs[q*8+j], sbs[64+q*8+j]), 0.f);
            pk4.x = cvt_pk(f[0], f[1]);
            pk4.y = cvt_pk(f[2], f[3]);
            pk4.z = cvt_pk(f[4], f[5]);
            pk4.w = cvt_pk(f[6], f[7]);
        }
        *(uint4*)&lds[row*64 + ((q ^ (row & 7)))*8] = pk4;
    }

    f32x4 acc[8];
    #pragma unroll
    for (int i = 0; i < 8; ++i) acc[i] = (f32x4){0.f,0.f,0.f,0.f};
    float tbc[4];
    #pragma unroll
    for (int r = 0; r < 4; ++r) tbc[r] = tb[cbase + r];

    __syncthreads();

    #pragma unroll
    for (int ks = 0; ks < 2; ++ks) {
        bf16x8 af[9];
        #pragma unroll
        for (int dt = 0; dt < 9; ++dt)
            af[dt] = *(const bf16x8*)&twb[((2*dt + ks)*64 + cA)*32 + 8*lg];
        #pragma unroll
        for (int jt = 0; jt < 8; ++jt) {
            #pragma unroll
            for (int dt = 0; dt < 9; ++dt) {
                int row = 16*jt + lr + 25*dt;            // [0, 328)
                bf16x8 b = *(const bf16x8*)&lds[row*64 + ((4*ks + lg) ^ (row & 7))*8];
                acc[jt] = __builtin_amdgcn_mfma_f32_16x16x32_bf16(af[dt], b, acc[jt], 0, 0, 0);
            }
        }
    }

    float sacc[4] = {0,0,0,0}, qacc[4] = {0,0,0,0};
    #pragma unroll
    for (int jt = 0; jt < 8; ++jt) {
        int j = j0 + 16*jt + lr;
        if (j < 7500) {
            #pragma unroll
            for (int r = 0; r < 4; ++r) {
                float v = acc[jt][r] + tbc[r];
                sacc[r] += v; qacc[r] += v*v;
            }
        }
    }
    #pragma unroll
    for (int r = 0; r < 4; ++r) {
        float s = sacc[r], q = qacc[r];
        s += __shfl_xor(s, 1); s += __shfl_xor(s, 2);
        s += __shfl_xor(s, 4); s += __shfl_xor(s, 8);
        q += __shfl_xor(q, 1); q += __shfl_xor(q, 2);
        q += __shfl_xor(q, 4); q += __shfl_xor(q, 8);
        if (lr == 0) {
            float* dst = stats4 + (size_t)(n*59 + bj)*128;
            dst[cbase + r] = s;
            dst[64 + cbase + r] = q;
        }
    }

    __syncthreads();
    #pragma unroll
    for (int jt = 0; jt < 8; ++jt)
        #pragma unroll
        for (int r = 0; r < 4; ++r)
            lds[(cbase + r)*136 + 16*jt + lr] = f2bf(acc[jt][r] + tbc[r]);
    __syncthreads();
    for (int e = tid; e < 2048; e += 256) {
        int row = e >> 5, c4 = (e & 31) << 2;
        int j = j0 + c4;
        if (j < 7500)
            *(s4v*)&hout[(size_t)(n*64 + row)*7500 + j] = *(const s4v*)&lds[row*136 + c4];
    }
}

// ---------------------------------------------------------------------------
// k_out: out = relu(bn2(h) + x) f32
// ---------------------------------------------------------------------------
__global__ __launch_bounds__(256) void k_out(
    const unsigned short* __restrict__ h, const float* __restrict__ x,
    const float* __restrict__ sb, float* __restrict__ out)
{
    int i4 = blockIdx.x * 256 + threadIdx.x;
    if (i4 >= NELEM/4) return;
    int c = ((i4*4) / TV) & 63;
    float s2 = sb[128 + c], b2 = sb[192 + c];
    s4v hv = *(const s4v*)&h[i4*4];
    float4 xv = ((const float4*)x)[i4];
    float4 o;
    o.x = fmaxf(fmaf(bf2f((unsigned short)hv[0]), s2, b2) + xv.x, 0.f);
    o.y = fmaxf(fmaf(bf2f((unsigned short)hv[1]), s2, b2) + xv.y, 0.f);
    o.z = fmaxf(fmaf(bf2f((unsigned short)hv[2]), s2, b2) + xv.z, 0.f);
    o.w = fmaxf(fmaf(bf2f((unsigned short)hv[3]), s2, b2) + xv.w, 0.f);
    ((float4*)out)[i4] = o;
}

// ---------------------------------------------------------------------------
extern "C" void kernel_launch(void* const* d_in, const int* in_sizes, int n_in,
                              void* d_out, int out_size, void* d_ws, size_t ws_size,
                              hipStream_t stream)
{
    const float* x      = (const float*)d_in[0];
    const float* A      = (const float*)d_in[1];
    const float* B      = (const float*)d_in[2];
    const float* lamda  = (const float*)d_in[3];
    const float* conv_w = (const float*)d_in[4];
    const float* conv_b = (const float*)d_in[5];
    const float* bn1_g  = (const float*)d_in[6];
    const float* bn1_b  = (const float*)d_in[7];
    const float* tcn_w  = (const float*)d_in[8];
    const float* tcn_b  = (const float*)d_in[9];
    const float* bn2_g  = (const float*)d_in[10];
    const float* bn2_b  = (const float*)d_in[11];

    unsigned short* g = (unsigned short*)d_ws;          // NELEM bf16
    unsigned short* h = g + NELEM;                      // NELEM bf16
    float* stats3 = (float*)(h + NELEM);                // 1920*128
    float* stats4 = stats3 + 1920*128;                  // 1888*128
    float* sb     = stats4 + 1888*128;                  // 256
    float* csumN  = sb + 256;                           // 32*160
    unsigned short* w2b  = (unsigned short*)(csumN + 32*160);  // 20480
    unsigned short* twb  = w2b + 20480;                 // 36864
    unsigned short* ashA = twb + 36864;                 // 3840
    unsigned short* bshB = ashA + 3840;                 // 32*2560

    k_prep<<<32, 256, 0, stream>>>(conv_w, tcn_w, A, w2b, twb, ashA);
    k_prepn<<<32, 256, 0, stream>>>(A, B, lamda, bshB, csumN);
    k_gcn<<<dim3(60, N_), 256, 0, stream>>>(x, ashA, bshB, csumN, w2b, conv_b, g, stats3);
    k_fin<<<64, 256, 0, stream>>>(stats3, 1920, sb, bn1_g, bn1_b);
    k_tcn<<<dim3(59, N_), 256, 0, stream>>>(g, sb, twb, tcn_b, h, stats4);
    k_fin<<<64, 256, 0, stream>>>(stats4, 1888, sb + 128, bn2_g, bn2_b);
    k_out<<<NELEM/4/256, 256, 0, stream>>>(h, x, sb, (float*)d_out);
}

// Round 14
// 131.705 us; speedup vs baseline: 1.0960x; 1.0960x over previous
//
#include <hip/hip_runtime.h>
#include <hip/hip_bf16.h>

#define N_  32
#define C_  64
#define T_  300
#define V_  25
#define TV  (T_*V_)        // 7500
#define CTV (C_*TV)        // 480000
#define NELEM (N_*CTV)     // 15360000
#define CNTF 240000.0f

typedef float f32x4 __attribute__((ext_vector_type(4)));
typedef short bf16x8 __attribute__((ext_vector_type(8)));
typedef short s4v __attribute__((ext_vector_type(4)));
typedef short s8v __attribute__((ext_vector_type(8)));

__device__ __forceinline__ unsigned short f2bf(float f) {
    unsigned u = __float_as_uint(f);
    unsigned r = u + 0x7fffu + ((u >> 16) & 1u);
    return (unsigned short)(r >> 16);
}
__device__ __forceinline__ float bf2f(unsigned short u) {
    return __uint_as_float(((unsigned)u) << 16);
}
// HW packed f32->bf16 (RNE)
__device__ __forceinline__ unsigned cvt_pk(float lo, float hi) {
    unsigned r;
    asm("v_cvt_pk_bf16_f32 %0, %1, %2" : "=v"(r) : "v"(lo), "v"(hi));
    return r;
}

// ---------------------------------------------------------------------------
// k_prep: weights -> bf16 MFMA layouts; A -> transposed bf16 [k3][w32][v40].
// ---------------------------------------------------------------------------
__global__ __launch_bounds__(256) void k_prep(
    const float* __restrict__ conv_w, const float* __restrict__ tw,
    const float* __restrict__ A,
    unsigned short* __restrict__ w2b, unsigned short* __restrict__ twb,
    unsigned short* __restrict__ ashA)
{
    int tid = blockIdx.x*256 + threadIdx.x;
    for (int e = tid; e < 20480; e += 8192) {
        int ks = e >> 11, c = (e >> 5) & 63, kk = e & 31;
        w2b[e] = f2bf(conv_w[(((ks>>1)*64 + c)*64) + (ks&1)*32 + kk]);
    }
    for (int e = tid; e < 36864; e += 8192) {
        int gi = e >> 11, c = (e >> 5) & 63, kk = e & 31;
        int dt = gi >> 1, ks = gi & 1;
        twb[e] = f2bf(tw[(c*64 + 32*ks + kk)*9 + dt]);
    }
    for (int e = tid; e < 3840; e += 8192) {
        int k = e / 1280, r = e - k*1280, w = r / 40, v = r % 40;
        float val = (w < 25 && v < 25) ? A[k*625 + v*25 + w] : 0.f;
        ashA[e] = f2bf(val);
    }
}

// ---------------------------------------------------------------------------
// k_prepn: per-n staging precompute. grid 32 (one block per n).
// ---------------------------------------------------------------------------
__global__ __launch_bounds__(256) void k_prepn(
    const float* __restrict__ A, const float* __restrict__ B,
    const float* __restrict__ lamda,
    unsigned short* __restrict__ bshB, float* __restrict__ csumN)
{
    const int n = blockIdx.x, tid = threadIdx.x;
    const float lam = lamda[0];
    unsigned short* dst = bshB + n*2560;
    {
        s8v z8 = {0,0,0,0,0,0,0,0};
        for (int e = tid; e < 320; e += 256) *(s8v*)&dst[e*8] = z8;
    }
    __syncthreads();
    for (int e = tid; e < 1250; e += 256) {
        int k = e / 625, r = e - k*625, v = r / 25, w = r - v*25;
        dst[k*1280 + w*40 + v] = f2bf(lam * B[((n<<1) + k)*625 + r]);
    }
    for (int e = tid; e < 160; e += 256) {
        int k = e / 32, w = e % 32;
        float s = 0.f;
        if (w < 25) {
            if (k < 3) { for (int v = 0; v < 25; ++v) s += bf2f(f2bf(A[k*625 + v*25 + w])); }
            else       { for (int v = 0; v < 25; ++v) s += bf2f(f2bf(lam * B[((n<<1)+(k-3))*625 + v*25 + w])); }
        }
        csumN[n*160 + e] = s;
    }
}

// ---------------------------------------------------------------------------
// k_gcn v8: r12 kernel + t-PAIRING ONLY. grid (30,32), TC=10 = 5 pairs.
// Per pair: step1 for both t (20 indep MFMA, B-frags from stable ash LDS)
// -> zsh[0], zsh[1]; ONE barrier; step2 (4 indep 10-chains); stores; barrier.
// No register-hoisting of frags, no LDS buffer aliasing (r8 lessons).
// ---------------------------------------------------------------------------
__global__ __launch_bounds__(256) void k_gcn(
    const float* __restrict__ x,
    const unsigned short* __restrict__ ashA, const unsigned short* __restrict__ bshB,
    const float* __restrict__ csumN,
    const unsigned short* __restrict__ w2b, const float* __restrict__ conv_b,
    unsigned short* __restrict__ gout, float* __restrict__ stats3)
{
    __shared__ unsigned short ash[6400];       // aeff^T [k5][w32][v40], never clobbered
    __shared__ unsigned short zsh[2][10496];   // z for t-pair

    const int tb = blockIdx.x, n = blockIdx.y;
    const int t0 = tb*10;
    const int tid = threadIdx.x;
    const int lane = tid & 63, wv = tid >> 6;
    const int lg = lane >> 4, lr = lane & 15;
    const int crow = lr + 16*wv;
    const int cbase = 16*wv + 4*lg;

    bf16x8 wfrag[10];
    #pragma unroll
    for (int ks = 0; ks < 10; ++ks)
        wfrag[ks] = *(const bf16x8*)&w2b[(ks*64 + crow)*32 + 8*lg];

    // staging: pure vector copies (pads pre-zeroed in ashA/bshB)
    for (int e = tid; e < 480; e += 256)
        *(s8v*)&ash[e*8] = *(const s8v*)&ashA[e*8];
    for (int e = tid; e < 320; e += 256)
        *(s8v*)&ash[3840 + e*8] = *(const s8v*)&bshB[n*2560 + e*8];

    const float* csum = csumN + n*160;
    float bs0[4], bs1[4];
    #pragma unroll
    for (int r = 0; r < 4; ++r) {
        float s0 = 0.f, s1 = 0.f;
        #pragma unroll
        for (int k = 0; k < 5; ++k) {
            float cb = conv_b[k*64 + cbase + r];
            s0 += cb * csum[k*32 + lr];
            s1 += cb * csum[k*32 + lr + 16];
        }
        bs0[r] = s0; bs1[r] = s1;
    }

    float sacc[4] = {0,0,0,0}, qacc[4] = {0,0,0,0};

    const float* xrow = x + n*CTV + crow*TV + t0*V_;
    float xf0[8], xf1[8];
    #pragma unroll
    for (int i = 0; i < 8; ++i) {
        int v = 8*lg + i;
        xf0[i] = (v < 25) ? xrow[v] : 0.f;
        xf1[i] = (v < 25) ? xrow[V_ + v] : 0.f;
    }

    __syncthreads();   // ash staged

    for (int tp = 0; tp < 5; ++tp) {
        union { bf16x8 v; unsigned u[4]; } xu0, xu1;
        #pragma unroll
        for (int p = 0; p < 4; ++p) {
            xu0.u[p] = cvt_pk(xf0[2*p], xf0[2*p+1]);
            xu1.u[p] = cvt_pk(xf1[2*p], xf1[2*p+1]);
        }
        bf16x8 xg0 = xu0.v, xg1 = xu1.v;
        if (tp < 4) {
            const float* xn = xrow + (2*tp + 2)*V_;
            #pragma unroll
            for (int i = 0; i < 8; ++i) {
                int v = 8*lg + i;
                xf0[i] = (v < 25) ? xn[v] : 0.f;
                xf1[i] = (v < 25) ? xn[V_ + v] : 0.f;
            }
        }
        // step1 for both t: B-frags fresh from stable ash
        #pragma unroll
        for (int k = 0; k < 5; ++k)
        #pragma unroll
        for (int nt = 0; nt < 2; ++nt) {
            bf16x8 bfrag = *(const bf16x8*)&ash[k*1280 + (lr + 16*nt)*40 + 8*lg];
            f32x4 z0 = {0.f,0.f,0.f,0.f}, z1 = {0.f,0.f,0.f,0.f};
            z0 = __builtin_amdgcn_mfma_f32_16x16x32_bf16(xg0, bfrag, z0, 0, 0, 0);
            z1 = __builtin_amdgcn_mfma_f32_16x16x32_bf16(xg1, bfrag, z1, 0, 0, 0);
            uint2 p0, p1;
            p0.x = cvt_pk(z0[0], z0[1]); p0.y = cvt_pk(z0[2], z0[3]);
            p1.x = cvt_pk(z1[0], z1[1]); p1.y = cvt_pk(z1[2], z1[3]);
            const int zoff = (lr + 16*nt)*328 + k*64 + 16*wv + 4*lg;
            *(uint2*)&zsh[0][zoff] = p0;
            *(uint2*)&zsh[1][zoff] = p1;
        }
        __syncthreads();
        // step2 for both t: 4 independent chains
        f32x4 a00 = {0.f,0.f,0.f,0.f}, a01 = {0.f,0.f,0.f,0.f};
        f32x4 a10 = {0.f,0.f,0.f,0.f}, a11 = {0.f,0.f,0.f,0.f};
        #pragma unroll
        for (int ks = 0; ks < 10; ++ks) {
            bf16x8 b00 = *(const bf16x8*)&zsh[0][lr*328 + 32*ks + 8*lg];
            bf16x8 b01 = *(const bf16x8*)&zsh[0][(lr+16)*328 + 32*ks + 8*lg];
            bf16x8 b10 = *(const bf16x8*)&zsh[1][lr*328 + 32*ks + 8*lg];
            bf16x8 b11 = *(const bf16x8*)&zsh[1][(lr+16)*328 + 32*ks + 8*lg];
            a00 = __builtin_amdgcn_mfma_f32_16x16x32_bf16(wfrag[ks], b00, a00, 0, 0, 0);
            a01 = __builtin_amdgcn_mfma_f32_16x16x32_bf16(wfrag[ks], b01, a01, 0, 0, 0);
            a10 = __builtin_amdgcn_mfma_f32_16x16x32_bf16(wfrag[ks], b10, a10, 0, 0, 0);
            a11 = __builtin_amdgcn_mfma_f32_16x16x32_bf16(wfrag[ks], b11, a11, 0, 0, 0);
        }
        // epilogue for both t
        float v00[4], v01[4], v10[4], v11[4];
        #pragma unroll
        for (int r = 0; r < 4; ++r) {
            v00[r] = a00[r] + bs0[r]; v01[r] = a01[r] + bs1[r];
            v10[r] = a10[r] + bs0[r]; v11[r] = a11[r] + bs1[r];
            sacc[r] += v00[r] + v10[r] + (lr < 9 ? v01[r] + v11[r] : 0.f);
            qacc[r] += v00[r]*v00[r] + v10[r]*v10[r]
                     + (lr < 9 ? v01[r]*v01[r] + v11[r]*v11[r] : 0.f);
        }
        unsigned short* grow0 = gout + (size_t)(n*300 + t0 + 2*tp)*1600;
        unsigned short* grow1 = grow0 + 1600;
        uint2 ga, gb;
        ga.x = cvt_pk(v00[0], v00[1]); ga.y = cvt_pk(v00[2], v00[3]);
        gb.x = cvt_pk(v01[0], v01[1]); gb.y = cvt_pk(v01[2], v01[3]);
        *(uint2*)&grow0[lr*64 + cbase] = ga;
        if (lr < 9) *(uint2*)&grow0[(lr+16)*64 + cbase] = gb;
        ga.x = cvt_pk(v10[0], v10[1]); ga.y = cvt_pk(v10[2], v10[3]);
        gb.x = cvt_pk(v11[0], v11[1]); gb.y = cvt_pk(v11[2], v11[3]);
        *(uint2*)&grow1[lr*64 + cbase] = ga;
        if (lr < 9) *(uint2*)&grow1[(lr+16)*64 + cbase] = gb;
        __syncthreads();
    }

    #pragma unroll
    for (int r = 0; r < 4; ++r) {
        float s = sacc[r], q = qacc[r];
        s += __shfl_xor(s, 1); s += __shfl_xor(s, 2);
        s += __shfl_xor(s, 4); s += __shfl_xor(s, 8);
        q += __shfl_xor(q, 1); q += __shfl_xor(q, 2);
        q += __shfl_xor(q, 4); q += __shfl_xor(q, 8);
        if (lr == 0) {
            stats3[(n*30 + tb)*128 + cbase + r] = s;
            stats3[(n*30 + tb)*128 + 64 + cbase + r] = q;
        }
    }
}

// ---------------------------------------------------------------------------
// k_fin: reduce per-block stats -> BN scale/shift. grid 64.
// ---------------------------------------------------------------------------
__global__ __launch_bounds__(256) void k_fin(
    const float* __restrict__ src, int count, float* __restrict__ sbo,
    const float* __restrict__ gma, const float* __restrict__ bta)
{
    const int c = blockIdx.x, tid = threadIdx.x;
    float s = 0.f, q = 0.f;
    for (int b = tid; b < count; b += 256) {
        s += src[b*128 + c];
        q += src[b*128 + 64 + c];
    }
    #pragma unroll
    for (int m = 1; m < 64; m <<= 1) { s += __shfl_xor(s, m); q += __shfl_xor(q, m); }
    __shared__ float rs[4], rq[4];
    if ((tid & 63) == 0) { rs[tid>>6] = s; rq[tid>>6] = q; }
    __syncthreads();
    if (tid == 0) {
        s = rs[0]+rs[1]+rs[2]+rs[3]; q = rq[0]+rq[1]+rq[2]+rq[3];
        float mean = s / CNTF, var = q / CNTF - mean*mean;
        float sc = gma[c] * rsqrtf(var + 1e-5f);
        sbo[c] = sc;
        sbo[64 + c] = bta[c] - mean*sc;
    }
}

// ---------------------------------------------------------------------------
// k_tcn v6 (r13, validated): grid (59,32), 256 thr; bn1+relu fused staging.
// ---------------------------------------------------------------------------
__global__ __launch_bounds__(256) void k_tcn(
    const unsigned short* __restrict__ g, const float* __restrict__ sb,
    const unsigned short* __restrict__ twb, const float* __restrict__ tb,
    unsigned short* __restrict__ hout, float* __restrict__ stats4)
{
    __shared__ unsigned short lds[328*64];   // 41984 B; reused as hbuf[64][136]
    __shared__ float sbs[128];

    const int bj = blockIdx.x, n = blockIdx.y;
    const int j0 = bj*128;
    const int tid = threadIdx.x;
    const int lane = tid & 63, ct = tid >> 6;
    const int lg = lane >> 4, lr = lane & 15;
    const int cA = ct*16 + lr;
    const int cbase = ct*16 + 4*lg;

    if (tid < 128) sbs[tid] = sb[tid];
    __syncthreads();

    for (int e = tid; e < 2624; e += 256) {
        int row = e >> 3, q = e & 7;
        int gr = j0 - 100 + row;
        uint4 pk4 = {0,0,0,0};
        if (gr >= 0 && gr < 7500) {
            s8v raw = *(const s8v*)&g[((size_t)n*7500 + gr)*64 + q*8];
            float f[8];
            #pragma unroll
            for (int j = 0; j < 8; ++j)
                f[j] = fmaxf(fmaf(bf2f((unsigned short)raw[j]), sbs[q*8+j], sbs[64+q*8+j]), 0.f);
            pk4.x = cvt_pk(f[0], f[1]);
            pk4.y = cvt_pk(f[2], f[3]);
            pk4.z = cvt_pk(f[4], f[5]);
            pk4.w = cvt_pk(f[6], f[7]);
        }
        *(uint4*)&lds[row*64 + ((q ^ (row & 7)))*8] = pk4;
    }

    f32x4 acc[8];
    #pragma unroll
    for (int i = 0; i < 8; ++i) acc[i] = (f32x4){0.f,0.f,0.f,0.f};
    float tbc[4];
    #pragma unroll
    for (int r = 0; r < 4; ++r) tbc[r] = tb[cbase + r];

    __syncthreads();

    #pragma unroll
    for (int ks = 0; ks < 2; ++ks) {
        bf16x8 af[9];
        #pragma unroll
        for (int dt = 0; dt < 9; ++dt)
            af[dt] = *(const bf16x8*)&twb[((2*dt + ks)*64 + cA)*32 + 8*lg];
        #pragma unroll
        for (int jt = 0; jt < 8; ++jt) {
            #pragma unroll
            for (int dt = 0; dt < 9; ++dt) {
                int row = 16*jt + lr + 25*dt;            // [0, 328)
                bf16x8 b = *(const bf16x8*)&lds[row*64 + ((4*ks + lg) ^ (row & 7))*8];
                acc[jt] = __builtin_amdgcn_mfma_f32_16x16x32_bf16(af[dt], b, acc[jt], 0, 0, 0);
            }
        }
    }

    float sacc[4] = {0,0,0,0}, qacc[4] = {0,0,0,0};
    #pragma unroll
    for (int jt = 0; jt < 8; ++jt) {
        int j = j0 + 16*jt + lr;
        if (j < 7500) {
            #pragma unroll
            for (int r = 0; r < 4; ++r) {
                float v = acc[jt][r] + tbc[r];
                sacc[r] += v; qacc[r] += v*v;
            }
        }
    }
    #pragma unroll
    for (int r = 0; r < 4; ++r) {
        float s = sacc[r], q = qacc[r];
        s += __shfl_xor(s, 1); s += __shfl_xor(s, 2);
        s += __shfl_xor(s, 4); s += __shfl_xor(s, 8);
        q += __shfl_xor(q, 1); q += __shfl_xor(q, 2);
        q += __shfl_xor(q, 4); q += __shfl_xor(q, 8);
        if (lr == 0) {
            float* dst = stats4 + (size_t)(n*59 + bj)*128;
            dst[cbase + r] = s;
            dst[64 + cbase + r] = q;
        }
    }

    __syncthreads();
    #pragma unroll
    for (int jt = 0; jt < 8; ++jt)
        #pragma unroll
        for (int r = 0; r < 4; ++r)
            lds[(cbase + r)*136 + 16*jt + lr] = f2bf(acc[jt][r] + tbc[r]);
    __syncthreads();
    for (int e = tid; e < 2048; e += 256) {
        int row = e >> 5, c4 = (e & 31) << 2;
        int j = j0 + c4;
        if (j < 7500)
            *(s4v*)&hout[(size_t)(n*64 + row)*7500 + j] = *(const s4v*)&lds[row*136 + c4];
    }
}

// ---------------------------------------------------------------------------
// k_out: out = relu(bn2(h) + x) f32
// ---------------------------------------------------------------------------
__global__ __launch_bounds__(256) void k_out(
    const unsigned short* __restrict__ h, const float* __restrict__ x,
    const float* __restrict__ sb, float* __restrict__ out)
{
    int i4 = blockIdx.x * 256 + threadIdx.x;
    if (i4 >= NELEM/4) return;
    int c = ((i4*4) / TV) & 63;
    float s2 = sb[128 + c], b2 = sb[192 + c];
    s4v hv = *(const s4v*)&h[i4*4];
    float4 xv = ((const float4*)x)[i4];
    float4 o;
    o.x = fmaxf(fmaf(bf2f((unsigned short)hv[0]), s2, b2) + xv.x, 0.f);
    o.y = fmaxf(fmaf(bf2f((unsigned short)hv[1]), s2, b2) + xv.y, 0.f);
    o.z = fmaxf(fmaf(bf2f((unsigned short)hv[2]), s2, b2) + xv.z, 0.f);
    o.w = fmaxf(fmaf(bf2f((unsigned short)hv[3]), s2, b2) + xv.w, 0.f);
    ((float4*)out)[i4] = o;
}

// ---------------------------------------------------------------------------
extern "C" void kernel_launch(void* const* d_in, const int* in_sizes, int n_in,
                              void* d_out, int out_size, void* d_ws, size_t ws_size,
                              hipStream_t stream)
{
    const float* x      = (const float*)d_in[0];
    const float* A      = (const float*)d_in[1];
    const float* B      = (const float*)d_in[2];
    const float* lamda  = (const float*)d_in[3];
    const float* conv_w = (const float*)d_in[4];
    const float* conv_b = (const float*)d_in[5];
    const float* bn1_g  = (const float*)d_in[6];
    const float* bn1_b  = (const float*)d_in[7];
    const float* tcn_w  = (const float*)d_in[8];
    const float* tcn_b  = (const float*)d_in[9];
    const float* bn2_g  = (const float*)d_in[10];
    const float* bn2_b  = (const float*)d_in[11];

    unsigned short* g = (unsigned short*)d_ws;          // NELEM bf16
    unsigned short* h = g + NELEM;                      // NELEM bf16
    float* stats3 = (float*)(h + NELEM);                // 960*128
    float* stats4 = stats3 + 960*128;                   // 1888*128
    float* sb     = stats4 + 1888*128;                  // 256
    float* csumN  = sb + 256;                           // 32*160
    unsigned short* w2b  = (unsigned short*)(csumN + 32*160);  // 20480
    unsigned short* twb  = w2b + 20480;                 // 36864
    unsigned short* ashA = twb + 36864;                 // 3840
    unsigned short* bshB = ashA + 3840;                 // 32*2560

    k_prep<<<32, 256, 0, stream>>>(conv_w, tcn_w, A, w2b, twb, ashA);
    k_prepn<<<32, 256, 0, stream>>>(A, B, lamda, bshB, csumN);
    k_gcn<<<dim3(30, N_), 256, 0, stream>>>(x, ashA, bshB, csumN, w2b, conv_b, g, stats3);
    k_fin<<<64, 256, 0, stream>>>(stats3, 960, sb, bn1_g, bn1_b);
    k_tcn<<<dim3(59, N_), 256, 0, stream>>>(g, sb, twb, tcn_b, h, stats4);
    k_fin<<<64, 256, 0, stream>>>(stats4, 1888, sb + 128, bn2_g, bn2_b);
    k_out<<<NELEM/4/256, 256, 0, stream>>>(h, x, sb, (float*)d_out);
}

// Round 16
// 127.527 us; speedup vs baseline: 1.1319x; 1.0328x over previous
//
#include <hip/hip_runtime.h>
#include <hip/hip_bf16.h>

#define N_  32
#define C_  64
#define T_  300
#define V_  25
#define TV  (T_*V_)        // 7500
#define CTV (C_*TV)        // 480000
#define NELEM (N_*CTV)     // 15360000
#define CNTF 240000.0f

typedef float f32x4 __attribute__((ext_vector_type(4)));
typedef short bf16x8 __attribute__((ext_vector_type(8)));
typedef short s4v __attribute__((ext_vector_type(4)));
typedef short s8v __attribute__((ext_vector_type(8)));

__device__ __forceinline__ unsigned short f2bf(float f) {
    unsigned u = __float_as_uint(f);
    unsigned r = u + 0x7fffu + ((u >> 16) & 1u);
    return (unsigned short)(r >> 16);
}
__device__ __forceinline__ float bf2f(unsigned short u) {
    return __uint_as_float(((unsigned)u) << 16);
}
// HW packed f32->bf16 (RNE)
__device__ __forceinline__ unsigned cvt_pk(float lo, float hi) {
    unsigned r;
    asm("v_cvt_pk_bf16_f32 %0, %1, %2" : "=v"(r) : "v"(lo), "v"(hi));
    return r;
}

// ---------------------------------------------------------------------------
// k_prep (merged): weights -> bf16 MFMA layouts; A -> transposed bf16;
// per-n B staging + csum. grid 32 x 256.
// ---------------------------------------------------------------------------
__global__ __launch_bounds__(256) void k_prep(
    const float* __restrict__ conv_w, const float* __restrict__ tw,
    const float* __restrict__ A, const float* __restrict__ B,
    const float* __restrict__ lamda,
    unsigned short* __restrict__ w2b, unsigned short* __restrict__ twb,
    unsigned short* __restrict__ ashA, unsigned short* __restrict__ bshB,
    float* __restrict__ csumN)
{
    const int gtid = blockIdx.x*256 + threadIdx.x;
    for (int e = gtid; e < 20480; e += 8192) {
        int ks = e >> 11, c = (e >> 5) & 63, kk = e & 31;
        w2b[e] = f2bf(conv_w[(((ks>>1)*64 + c)*64) + (ks&1)*32 + kk]);
    }
    for (int e = gtid; e < 36864; e += 8192) {
        int gi = e >> 11, c = (e >> 5) & 63, kk = e & 31;
        int dt = gi >> 1, ks = gi & 1;
        twb[e] = f2bf(tw[(c*64 + 32*ks + kk)*9 + dt]);
    }
    for (int e = gtid; e < 3840; e += 8192) {
        int k = e / 1280, r = e - k*1280, w = r / 40, v = r % 40;
        float val = (w < 25 && v < 25) ? A[k*625 + v*25 + w] : 0.f;
        ashA[e] = f2bf(val);
    }
    // per-n part: n = blockIdx.x
    const int n = blockIdx.x, tid = threadIdx.x;
    const float lam = lamda[0];
    unsigned short* dst = bshB + n*2560;
    {
        s8v z8 = {0,0,0,0,0,0,0,0};
        for (int e = tid; e < 320; e += 256) *(s8v*)&dst[e*8] = z8;
    }
    __syncthreads();
    for (int e = tid; e < 1250; e += 256) {
        int k = e / 625, r = e - k*625, v = r / 25, w = r - v*25;
        dst[k*1280 + w*40 + v] = f2bf(lam * B[((n<<1) + k)*625 + r]);
    }
    for (int e = tid; e < 160; e += 256) {
        int k = e / 32, w = e % 32;
        float s = 0.f;
        if (w < 25) {
            if (k < 3) { for (int v = 0; v < 25; ++v) s += bf2f(f2bf(A[k*625 + v*25 + w])); }
            else       { for (int v = 0; v < 25; ++v) s += bf2f(f2bf(lam * B[((n<<1)+(k-3))*625 + v*25 + w])); }
        }
        csumN[n*160 + e] = s;
    }
}

// ---------------------------------------------------------------------------
// k_gcn v10: EXACT r14 (t-pairing) + step2 K-split (8 indep depth-5 chains).
// grid (30,32), TC=10 = 5 pairs. No cross-loop register carrying (r8/r15 ban).
// ---------------------------------------------------------------------------
__global__ __launch_bounds__(256) void k_gcn(
    const float* __restrict__ x,
    const unsigned short* __restrict__ ashA, const unsigned short* __restrict__ bshB,
    const float* __restrict__ csumN,
    const unsigned short* __restrict__ w2b, const float* __restrict__ conv_b,
    unsigned short* __restrict__ gout, float* __restrict__ stats3)
{
    __shared__ unsigned short ash[6400];       // aeff^T [k5][w32][v40], never clobbered
    __shared__ unsigned short zsh[2][10496];   // z for t-pair

    const int tb = blockIdx.x, n = blockIdx.y;
    const int t0 = tb*10;
    const int tid = threadIdx.x;
    const int lane = tid & 63, wv = tid >> 6;
    const int lg = lane >> 4, lr = lane & 15;
    const int crow = lr + 16*wv;
    const int cbase = 16*wv + 4*lg;

    bf16x8 wfrag[10];
    #pragma unroll
    for (int ks = 0; ks < 10; ++ks)
        wfrag[ks] = *(const bf16x8*)&w2b[(ks*64 + crow)*32 + 8*lg];

    // staging: pure vector copies (pads pre-zeroed in ashA/bshB)
    for (int e = tid; e < 480; e += 256)
        *(s8v*)&ash[e*8] = *(const s8v*)&ashA[e*8];
    for (int e = tid; e < 320; e += 256)
        *(s8v*)&ash[3840 + e*8] = *(const s8v*)&bshB[n*2560 + e*8];

    const float* csum = csumN + n*160;
    float bs0[4], bs1[4];
    #pragma unroll
    for (int r = 0; r < 4; ++r) {
        float s0 = 0.f, s1 = 0.f;
        #pragma unroll
        for (int k = 0; k < 5; ++k) {
            float cb = conv_b[k*64 + cbase + r];
            s0 += cb * csum[k*32 + lr];
            s1 += cb * csum[k*32 + lr + 16];
        }
        bs0[r] = s0; bs1[r] = s1;
    }

    float sacc[4] = {0,0,0,0}, qacc[4] = {0,0,0,0};

    const float* xrow = x + n*CTV + crow*TV + t0*V_;
    float xf0[8], xf1[8];
    #pragma unroll
    for (int i = 0; i < 8; ++i) {
        int v = 8*lg + i;
        xf0[i] = (v < 25) ? xrow[v] : 0.f;
        xf1[i] = (v < 25) ? xrow[V_ + v] : 0.f;
    }

    __syncthreads();   // ash staged

    for (int tp = 0; tp < 5; ++tp) {
        union { bf16x8 v; unsigned u[4]; } xu0, xu1;
        #pragma unroll
        for (int p = 0; p < 4; ++p) {
            xu0.u[p] = cvt_pk(xf0[2*p], xf0[2*p+1]);
            xu1.u[p] = cvt_pk(xf1[2*p], xf1[2*p+1]);
        }
        bf16x8 xg0 = xu0.v, xg1 = xu1.v;
        if (tp < 4) {
            const float* xn = xrow + (2*tp + 2)*V_;
            #pragma unroll
            for (int i = 0; i < 8; ++i) {
                int v = 8*lg + i;
                xf0[i] = (v < 25) ? xn[v] : 0.f;
                xf1[i] = (v < 25) ? xn[V_ + v] : 0.f;
            }
        }
        // step1 for both t: B-frags fresh from stable ash
        #pragma unroll
        for (int k = 0; k < 5; ++k)
        #pragma unroll
        for (int nt = 0; nt < 2; ++nt) {
            bf16x8 bfrag = *(const bf16x8*)&ash[k*1280 + (lr + 16*nt)*40 + 8*lg];
            f32x4 z0 = {0.f,0.f,0.f,0.f}, z1 = {0.f,0.f,0.f,0.f};
            z0 = __builtin_amdgcn_mfma_f32_16x16x32_bf16(xg0, bfrag, z0, 0, 0, 0);
            z1 = __builtin_amdgcn_mfma_f32_16x16x32_bf16(xg1, bfrag, z1, 0, 0, 0);
            uint2 p0, p1;
            p0.x = cvt_pk(z0[0], z0[1]); p0.y = cvt_pk(z0[2], z0[3]);
            p1.x = cvt_pk(z1[0], z1[1]); p1.y = cvt_pk(z1[2], z1[3]);
            const int zoff = (lr + 16*nt)*328 + k*64 + 16*wv + 4*lg;
            *(uint2*)&zsh[0][zoff] = p0;
            *(uint2*)&zsh[1][zoff] = p1;
        }
        __syncthreads();
        // step2 for both t: 8 independent depth-5 chains (K split 0-4 / 5-9)
        f32x4 a00 = {0.f,0.f,0.f,0.f}, a01 = {0.f,0.f,0.f,0.f};
        f32x4 a10 = {0.f,0.f,0.f,0.f}, a11 = {0.f,0.f,0.f,0.f};
        f32x4 c00 = {0.f,0.f,0.f,0.f}, c01 = {0.f,0.f,0.f,0.f};
        f32x4 c10 = {0.f,0.f,0.f,0.f}, c11 = {0.f,0.f,0.f,0.f};
        #pragma unroll
        for (int ks = 0; ks < 5; ++ks) {
            bf16x8 b00 = *(const bf16x8*)&zsh[0][lr*328 + 32*ks + 8*lg];
            bf16x8 b01 = *(const bf16x8*)&zsh[0][(lr+16)*328 + 32*ks + 8*lg];
            bf16x8 b10 = *(const bf16x8*)&zsh[1][lr*328 + 32*ks + 8*lg];
            bf16x8 b11 = *(const bf16x8*)&zsh[1][(lr+16)*328 + 32*ks + 8*lg];
            a00 = __builtin_amdgcn_mfma_f32_16x16x32_bf16(wfrag[ks], b00, a00, 0, 0, 0);
            a01 = __builtin_amdgcn_mfma_f32_16x16x32_bf16(wfrag[ks], b01, a01, 0, 0, 0);
            a10 = __builtin_amdgcn_mfma_f32_16x16x32_bf16(wfrag[ks], b10, a10, 0, 0, 0);
            a11 = __builtin_amdgcn_mfma_f32_16x16x32_bf16(wfrag[ks], b11, a11, 0, 0, 0);
            bf16x8 d00 = *(const bf16x8*)&zsh[0][lr*328 + 32*(ks+5) + 8*lg];
            bf16x8 d01 = *(const bf16x8*)&zsh[0][(lr+16)*328 + 32*(ks+5) + 8*lg];
            bf16x8 d10 = *(const bf16x8*)&zsh[1][lr*328 + 32*(ks+5) + 8*lg];
            bf16x8 d11 = *(const bf16x8*)&zsh[1][(lr+16)*328 + 32*(ks+5) + 8*lg];
            c00 = __builtin_amdgcn_mfma_f32_16x16x32_bf16(wfrag[ks+5], d00, c00, 0, 0, 0);
            c01 = __builtin_amdgcn_mfma_f32_16x16x32_bf16(wfrag[ks+5], d01, c01, 0, 0, 0);
            c10 = __builtin_amdgcn_mfma_f32_16x16x32_bf16(wfrag[ks+5], d10, c10, 0, 0, 0);
            c11 = __builtin_amdgcn_mfma_f32_16x16x32_bf16(wfrag[ks+5], d11, c11, 0, 0, 0);
        }
        // epilogue for both t (merge K-halves)
        float v00[4], v01[4], v10[4], v11[4];
        #pragma unroll
        for (int r = 0; r < 4; ++r) {
            v00[r] = a00[r] + c00[r] + bs0[r]; v01[r] = a01[r] + c01[r] + bs1[r];
            v10[r] = a10[r] + c10[r] + bs0[r]; v11[r] = a11[r] + c11[r] + bs1[r];
            sacc[r] += v00[r] + v10[r] + (lr < 9 ? v01[r] + v11[r] : 0.f);
            qacc[r] += v00[r]*v00[r] + v10[r]*v10[r]
                     + (lr < 9 ? v01[r]*v01[r] + v11[r]*v11[r] : 0.f);
        }
        unsigned short* grow0 = gout + (size_t)(n*300 + t0 + 2*tp)*1600;
        unsigned short* grow1 = grow0 + 1600;
        uint2 ga, gb;
        ga.x = cvt_pk(v00[0], v00[1]); ga.y = cvt_pk(v00[2], v00[3]);
        gb.x = cvt_pk(v01[0], v01[1]); gb.y = cvt_pk(v01[2], v01[3]);
        *(uint2*)&grow0[lr*64 + cbase] = ga;
        if (lr < 9) *(uint2*)&grow0[(lr+16)*64 + cbase] = gb;
        ga.x = cvt_pk(v10[0], v10[1]); ga.y = cvt_pk(v10[2], v10[3]);
        gb.x = cvt_pk(v11[0], v11[1]); gb.y = cvt_pk(v11[2], v11[3]);
        *(uint2*)&grow1[lr*64 + cbase] = ga;
        if (lr < 9) *(uint2*)&grow1[(lr+16)*64 + cbase] = gb;
        __syncthreads();
    }

    #pragma unroll
    for (int r = 0; r < 4; ++r) {
        float s = sacc[r], q = qacc[r];
        s += __shfl_xor(s, 1); s += __shfl_xor(s, 2);
        s += __shfl_xor(s, 4); s += __shfl_xor(s, 8);
        q += __shfl_xor(q, 1); q += __shfl_xor(q, 2);
        q += __shfl_xor(q, 4); q += __shfl_xor(q, 8);
        if (lr == 0) {
            stats3[(n*30 + tb)*128 + cbase + r] = s;
            stats3[(n*30 + tb)*128 + 64 + cbase + r] = q;
        }
    }
}

// ---------------------------------------------------------------------------
// k_fin: reduce per-block stats -> BN scale/shift. grid 64.
// ---------------------------------------------------------------------------
__global__ __launch_bounds__(256) void k_fin(
    const float* __restrict__ src, int count, float* __restrict__ sbo,
    const float* __restrict__ gma, const float* __restrict__ bta)
{
    const int c = blockIdx.x, tid = threadIdx.x;
    float s = 0.f, q = 0.f;
    for (int b = tid; b < count; b += 256) {
        s += src[b*128 + c];
        q += src[b*128 + 64 + c];
    }
    #pragma unroll
    for (int m = 1; m < 64; m <<= 1) { s += __shfl_xor(s, m); q += __shfl_xor(q, m); }
    __shared__ float rs[4], rq[4];
    if ((tid & 63) == 0) { rs[tid>>6] = s; rq[tid>>6] = q; }
    __syncthreads();
    if (tid == 0) {
        s = rs[0]+rs[1]+rs[2]+rs[3]; q = rq[0]+rq[1]+rq[2]+rq[3];
        float mean = s / CNTF, var = q / CNTF - mean*mean;
        float sc = gma[c] * rsqrtf(var + 1e-5f);
        sbo[c] = sc;
        sbo[64 + c] = bta[c] - mean*sc;
    }
}

// ---------------------------------------------------------------------------
// k_tcn v6 (r13/r14, validated): grid (59,32), 256 thr; bn1+relu fused staging.
// ---------------------------------------------------------------------------
__global__ __launch_bounds__(256) void k_tcn(
    const unsigned short* __restrict__ g, const float* __restrict__ sb,
    const unsigned short* __restrict__ twb, const float* __restrict__ tb,
    unsigned short* __restrict__ hout, float* __restrict__ stats4)
{
    __shared__ unsigned short lds[328*64];   // 41984 B; reused as hbuf[64][136]
    __shared__ float sbs[128];

    const int bj = blockIdx.x, n = blockIdx.y;
    const int j0 = bj*128;
    const int tid = threadIdx.x;
    const int lane = tid & 63, ct = tid >> 6;
    const int lg = lane >> 4, lr = lane & 15;
    const int cA = ct*16 + lr;
    const int cbase = ct*16 + 4*lg;

    if (tid < 128) sbs[tid] = sb[tid];
    __syncthreads();

    for (int e = tid; e < 2624; e += 256) {
        int row = e >> 3, q = e & 7;
        int gr = j0 - 100 + row;
        uint4 pk4 = {0,0,0,0};
        if (gr >= 0 && gr < 7500) {
            s8v raw = *(const s8v*)&g[((size_t)n*7500 + gr)*64 + q*8];
            float f[8];
            #pragma unroll
            for (int j = 0; j < 8; ++j)
                f[j] = fmaxf(fmaf(bf2f((unsigned short)raw[j]), sbs[q*8+j], sbs[64+q*8+j]), 0.f);
            pk4.x = cvt_pk(f[0], f[1]);
            pk4.y = cvt_pk(f[2], f[3]);
            pk4.z = cvt_pk(f[4], f[5]);
            pk4.w = cvt_pk(f[6], f[7]);
        }
        *(uint4*)&lds[row*64 + ((q ^ (row & 7)))*8] = pk4;
    }

    f32x4 acc[8];
    #pragma unroll
    for (int i = 0; i < 8; ++i) acc[i] = (f32x4){0.f,0.f,0.f,0.f};
    float tbc[4];
    #pragma unroll
    for (int r = 0; r < 4; ++r) tbc[r] = tb[cbase + r];

    __syncthreads();

    #pragma unroll
    for (int ks = 0; ks < 2; ++ks) {
        bf16x8 af[9];
        #pragma unroll
        for (int dt = 0; dt < 9; ++dt)
            af[dt] = *(const bf16x8*)&twb[((2*dt + ks)*64 + cA)*32 + 8*lg];
        #pragma unroll
        for (int jt = 0; jt < 8; ++jt) {
            #pragma unroll
            for (int dt = 0; dt < 9; ++dt) {
                int row = 16*jt + lr + 25*dt;            // [0, 328)
                bf16x8 b = *(const bf16x8*)&lds[row*64 + ((4*ks + lg) ^ (row & 7))*8];
                acc[jt] = __builtin_amdgcn_mfma_f32_16x16x32_bf16(af[dt], b, acc[jt], 0, 0, 0);
            }
        }
    }

    float sacc[4] = {0,0,0,0}, qacc[4] = {0,0,0,0};
    #pragma unroll
    for (int jt = 0; jt < 8; ++jt) {
        int j = j0 + 16*jt + lr;
        if (j < 7500) {
            #pragma unroll
            for (int r = 0; r < 4; ++r) {
                float v = acc[jt][r] + tbc[r];
                sacc[r] += v; qacc[r] += v*v;
            }
        }
    }
    #pragma unroll
    for (int r = 0; r < 4; ++r) {
        float s = sacc[r], q = qacc[r];
        s += __shfl_xor(s, 1); s += __shfl_xor(s, 2);
        s += __shfl_xor(s, 4); s += __shfl_xor(s, 8);
        q += __shfl_xor(q, 1); q += __shfl_xor(q, 2);
        q += __shfl_xor(q, 4); q += __shfl_xor(q, 8);
        if (lr == 0) {
            float* dst = stats4 + (size_t)(n*59 + bj)*128;
            dst[cbase + r] = s;
            dst[64 + cbase + r] = q;
        }
    }

    __syncthreads();
    #pragma unroll
    for (int jt = 0; jt < 8; ++jt)
        #pragma unroll
        for (int r = 0; r < 4; ++r)
            lds[(cbase + r)*136 + 16*jt + lr] = f2bf(acc[jt][r] + tbc[r]);
    __syncthreads();
    for (int e = tid; e < 2048; e += 256) {
        int row = e >> 5, c4 = (e & 31) << 2;
        int j = j0 + c4;
        if (j < 7500)
            *(s4v*)&hout[(size_t)(n*64 + row)*7500 + j] = *(const s4v*)&lds[row*136 + c4];
    }
}

// ---------------------------------------------------------------------------
// k_out: out = relu(bn2(h) + x) f32
// ---------------------------------------------------------------------------
__global__ __launch_bounds__(256) void k_out(
    const unsigned short* __restrict__ h, const float* __restrict__ x,
    const float* __restrict__ sb, float* __restrict__ out)
{
    int i4 = blockIdx.x * 256 + threadIdx.x;
    if (i4 >= NELEM/4) return;
    int c = ((i4*4) / TV) & 63;
    float s2 = sb[128 + c], b2 = sb[192 + c];
    s4v hv = *(const s4v*)&h[i4*4];
    float4 xv = ((const float4*)x)[i4];
    float4 o;
    o.x = fmaxf(fmaf(bf2f((unsigned short)hv[0]), s2, b2) + xv.x, 0.f);
    o.y = fmaxf(fmaf(bf2f((unsigned short)hv[1]), s2, b2) + xv.y, 0.f);
    o.z = fmaxf(fmaf(bf2f((unsigned short)hv[2]), s2, b2) + xv.z, 0.f);
    o.w = fmaxf(fmaf(bf2f((unsigned short)hv[3]), s2, b2) + xv.w, 0.f);
    ((float4*)out)[i4] = o;
}

// ---------------------------------------------------------------------------
extern "C" void kernel_launch(void* const* d_in, const int* in_sizes, int n_in,
                              void* d_out, int out_size, void* d_ws, size_t ws_size,
                              hipStream_t stream)
{
    const float* x      = (const float*)d_in[0];
    const float* A      = (const float*)d_in[1];
    const float* B      = (const float*)d_in[2];
    const float* lamda  = (const float*)d_in[3];
    const float* conv_w = (const float*)d_in[4];
    const float* conv_b = (const float*)d_in[5];
    const float* bn1_g  = (const float*)d_in[6];
    const float* bn1_b  = (const float*)d_in[7];
    const float* tcn_w  = (const float*)d_in[8];
    const float* tcn_b  = (const float*)d_in[9];
    const float* bn2_g  = (const float*)d_in[10];
    const float* bn2_b  = (const float*)d_in[11];

    unsigned short* g = (unsigned short*)d_ws;          // NELEM bf16
    unsigned short* h = g + NELEM;                      // NELEM bf16
    float* stats3 = (float*)(h + NELEM);                // 960*128
    float* stats4 = stats3 + 960*128;                   // 1888*128
    float* sb     = stats4 + 1888*128;                  // 256
    float* csumN  = sb + 256;                           // 32*160
    unsigned short* w2b  = (unsigned short*)(csumN + 32*160);  // 20480
    unsigned short* twb  = w2b + 20480;                 // 36864
    unsigned short* ashA = twb + 36864;                 // 3840
    unsigned short* bshB = ashA + 3840;                 // 32*2560

    k_prep<<<32, 256, 0, stream>>>(conv_w, tcn_w, A, B, lamda, w2b, twb, ashA, bshB, csumN);
    k_gcn<<<dim3(30, N_), 256, 0, stream>>>(x, ashA, bshB, csumN, w2b, conv_b, g, stats3);
    k_fin<<<64, 256, 0, stream>>>(stats3, 960, sb, bn1_g, bn1_b);
    k_tcn<<<dim3(59, N_), 256, 0, stream>>>(g, sb, twb, tcn_b, h, stats4);
    k_fin<<<64, 256, 0, stream>>>(stats4, 1888, sb + 128, bn2_g, bn2_b);
    k_out<<<NELEM/4/256, 256, 0, stream>>>(h, x, sb, (float*)d_out);
}